// Round 1
// baseline (215.869 us; speedup 1.0000x reference)
//
#include <hip/hip_runtime.h>
#include <hip/hip_bf16.h>
#include <math.h>

typedef __bf16 bfx4 __attribute__((ext_vector_type(4)));
typedef __bf16 bfx8 __attribute__((ext_vector_type(8)));
typedef float  f32x4 __attribute__((ext_vector_type(4)));

#define BATCH 16
#define NTOK  1024
#define CDIM  256
#define NHEAD 8
#define DHEAD 32
#define QKVD  768
#define INNER 256
#define SCALE 0.17677669529663687f

// ---------------- transpose fp32 [R][C] -> [C][R] per batch ----------------
__launch_bounds__(256)
__global__ void transpose_kernel(const float* __restrict__ in, float* __restrict__ out,
                                 int R, int Cc) {
  __shared__ float tile[32][33];
  int b = blockIdx.z;
  int c0 = blockIdx.x * 32, r0 = blockIdx.y * 32;
  const float* src = in + (size_t)b * R * Cc;
  float* dst = out + (size_t)b * R * Cc;
  int tx = threadIdx.x & 31, ty = threadIdx.x >> 5;   // 32 x 8
  #pragma unroll
  for (int i = 0; i < 4; ++i)
    tile[ty + i * 8][tx] = src[(size_t)(r0 + ty + i * 8) * Cc + c0 + tx];
  __syncthreads();
  #pragma unroll
  for (int i = 0; i < 4; ++i)
    dst[(size_t)(c0 + ty + i * 8) * R + r0 + tx] = tile[tx][ty + i * 8];
}

// ---------------- LayerNorm rows of 256, fp32 in -> bf16 out ----------------
__launch_bounds__(256)
__global__ void ln_kernel(const float* __restrict__ in, const float* __restrict__ g,
                          const float* __restrict__ bb, __bf16* __restrict__ out) {
  int row  = blockIdx.x * 4 + (threadIdx.x >> 6);
  int lane = threadIdx.x & 63;
  const float4 v = ((const float4*)(in + (size_t)row * 256))[lane];
  float s  = v.x + v.y + v.z + v.w;
  float s2 = v.x * v.x + v.y * v.y + v.z * v.z + v.w * v.w;
  #pragma unroll
  for (int o = 32; o; o >>= 1) { s += __shfl_xor(s, o); s2 += __shfl_xor(s2, o); }
  float mu  = s * 0.00390625f;
  float var = s2 * 0.00390625f - mu * mu;
  float rs  = rsqrtf(var + 1e-5f);
  const float4 gg = ((const float4*)g)[lane];
  const float4 bv = ((const float4*)bb)[lane];
  bfx4 o4;
  o4[0] = (__bf16)((v.x - mu) * rs * gg.x + bv.x);
  o4[1] = (__bf16)((v.y - mu) * rs * gg.y + bv.y);
  o4[2] = (__bf16)((v.z - mu) * rs * gg.z + bv.z);
  o4[3] = (__bf16)((v.w - mu) * rs * gg.w + bv.w);
  *(bfx4*)(out + (size_t)row * 256 + lane * 4) = o4;
}

// ---------------- weight transpose+cast: W[K][N] fp32 -> Wt[N][K] bf16 ------
__launch_bounds__(256)
__global__ void wprep_kernel(const float* __restrict__ W, __bf16* __restrict__ Wt,
                             int K, int Nn) {
  int idx = blockIdx.x * 256 + threadIdx.x;
  if (idx >= K * Nn) return;
  int n = idx / K, k = idx % K;
  Wt[idx] = (__bf16)W[(size_t)k * Nn + n];
}

// ---------------- bias precompute: biasT[h][k][q] bf16 ----------------------
__launch_bounds__(256)
__global__ void bias_kernel(const float* __restrict__ table, __bf16* __restrict__ biasT) {
  int idx = blockIdx.x * 256 + threadIdx.x;      // h*2^20 + k*2^10 + q
  int q = idx & 1023, k = (idx >> 10) & 1023, h = idx >> 20;
  int qi = q >> 5, qj = q & 31, ki = k >> 5, kj = k & 31;
  int r = (qi - ki + 31) * 63 + (qj - kj + 31);
  biasT[idx] = (__bf16)table[r * 8 + h];
}

// ---------------- GEMM: C[M][N] = A[M][K] @ Bt[N][K]^T ----------------------
// EPI 0: store bf16.  EPI 1: +bias[n] +resid[m][n] -> fp32.  EPI 2: +bias, GELU -> bf16.
template <int EPI>
__launch_bounds__(256)
__global__ void gemm_kernel(const __bf16* __restrict__ A, const __bf16* __restrict__ Bt,
                            const float* __restrict__ bias, const float* __restrict__ resid,
                            void* __restrict__ outp, int M, int Nn, int K) {
  __shared__ __bf16 As[64][40];
  __shared__ __bf16 Bs[64][40];
  const int m0 = blockIdx.x * 64, n0 = blockIdx.y * 64;
  const int t = threadIdx.x, lane = t & 63, w = t >> 6;
  const int arow = t >> 2, acol = (t & 3) * 8;
  const int lr = lane & 15, kb = (lane >> 4) * 4;
  f32x4 acc[4] = {};
  for (int k0 = 0; k0 < K; k0 += 32) {
    __syncthreads();
    *(bfx8*)&As[arow][acol] = *(const bfx8*)&A[(size_t)(m0 + arow) * K + k0 + acol];
    *(bfx8*)&Bs[arow][acol] = *(const bfx8*)&Bt[(size_t)(n0 + arow) * K + k0 + acol];
    __syncthreads();
    bfx4 alo = *(const bfx4*)&As[16 * w + lr][kb];
    bfx4 ahi = *(const bfx4*)&As[16 * w + lr][kb + 16];
    bfx8 af = __builtin_shufflevector(alo, ahi, 0, 1, 2, 3, 4, 5, 6, 7);
    #pragma unroll
    for (int c = 0; c < 4; ++c) {
      bfx4 blo = *(const bfx4*)&Bs[16 * c + lr][kb];
      bfx4 bhi = *(const bfx4*)&Bs[16 * c + lr][kb + 16];
      bfx8 bfr = __builtin_shufflevector(blo, bhi, 0, 1, 2, 3, 4, 5, 6, 7);
      acc[c] = __builtin_amdgcn_mfma_f32_16x16x32_bf16(af, bfr, acc[c], 0, 0, 0);
    }
  }
  #pragma unroll
  for (int c = 0; c < 4; ++c) {
    #pragma unroll
    for (int r = 0; r < 4; ++r) {
      int m = m0 + 16 * w + kb + r;     // C-frag row = (lane>>4)*4 + r
      int n = n0 + 16 * c + lr;         // C-frag col = lane&15
      float v = acc[c][r];
      if (EPI == 0) {
        ((__bf16*)outp)[(size_t)m * Nn + n] = (__bf16)v;
      } else if (EPI == 1) {
        v += bias[n] + resid[(size_t)m * Nn + n];
        ((float*)outp)[(size_t)m * Nn + n] = v;
      } else {
        v += bias[n];
        v = 0.5f * v * (1.0f + erff(v * 0.70710678118f));
        ((__bf16*)outp)[(size_t)m * Nn + n] = (__bf16)v;
      }
    }
  }
}

// ---------------- flash attention with relative-position bias ---------------
__launch_bounds__(256)
__global__ void attn_kernel(const __bf16* __restrict__ qkv, const __bf16* __restrict__ biasT,
                            __bf16* __restrict__ outb) {
  __shared__ __bf16 Qs[64][40];
  __shared__ __bf16 Ks[64][40];
  __shared__ __bf16 Vt[32][72];     // [d][k]
  __shared__ __bf16 Bls[64][72];    // [k][q]
  const int q0 = blockIdx.x * 64, h = blockIdx.y, b = blockIdx.z;
  const int t = threadIdx.x, lane = t & 63, w = t >> 6;
  const int lr = lane & 15, kb = (lane >> 4) * 4;
  const size_t qbase = (size_t)b * NTOK * QKVD;
  const int srow = t >> 2, sc8 = (t & 3) * 8;
  // stage Q (scaled into S later; raw here)
  *(bfx8*)&Qs[srow][sc8] = *(const bfx8*)&qkv[qbase + (size_t)(q0 + srow) * QKVD + h * DHEAD + sc8];
  __syncthreads();
  bfx4 qlo = *(const bfx4*)&Qs[16 * w + lr][kb];
  bfx4 qhi = *(const bfx4*)&Qs[16 * w + lr][kb + 16];
  bfx8 qf = __builtin_shufflevector(qlo, qhi, 0, 1, 2, 3, 4, 5, 6, 7);
  float m_run = -INFINITY, l_run = 0.f;
  f32x4 o0 = {}, o1 = {};
  for (int kt = 0; kt < 16; ++kt) {
    const int k0 = kt * 64;
    __syncthreads();
    {
      *(bfx8*)&Ks[srow][sc8] =
          *(const bfx8*)&qkv[qbase + (size_t)(k0 + srow) * QKVD + INNER + h * DHEAD + sc8];
      bfx8 v8 =
          *(const bfx8*)&qkv[qbase + (size_t)(k0 + srow) * QKVD + 2 * INNER + h * DHEAD + sc8];
      #pragma unroll
      for (int j = 0; j < 8; ++j) Vt[sc8 + j][srow] = v8[j];
      #pragma unroll
      for (int i = 0; i < 2; ++i) {
        int lin = t + i * 256;
        int kl = lin >> 3, q8 = (lin & 7) * 8;
        *(bfx8*)&Bls[kl][q8] =
            *(const bfx8*)&biasT[((size_t)h << 20) + ((size_t)(k0 + kl) << 10) + q0 + q8];
      }
    }
    __syncthreads();
    // S^T[k][q] = K @ Q^T
    f32x4 st[4];
    #pragma unroll
    for (int f = 0; f < 4; ++f) {
      bfx4 klo = *(const bfx4*)&Ks[16 * f + lr][kb];
      bfx4 khi = *(const bfx4*)&Ks[16 * f + lr][kb + 16];
      bfx8 kf = __builtin_shufflevector(klo, khi, 0, 1, 2, 3, 4, 5, 6, 7);
      f32x4 z = {};
      st[f] = __builtin_amdgcn_mfma_f32_16x16x32_bf16(kf, qf, z, 0, 0, 0);
    }
    float p[4][4], tmax = -INFINITY;
    #pragma unroll
    for (int f = 0; f < 4; ++f)
      #pragma unroll
      for (int r = 0; r < 4; ++r) {
        float bv = (float)Bls[16 * f + kb + r][16 * w + lr];
        float v = st[f][r] * SCALE + bv;
        p[f][r] = v;
        tmax = fmaxf(tmax, v);
      }
    tmax = fmaxf(tmax, __shfl_xor(tmax, 16));
    tmax = fmaxf(tmax, __shfl_xor(tmax, 32));
    float m_new = fmaxf(m_run, tmax);
    float fac = __expf(m_run - m_new);
    float tsum = 0.f;
    #pragma unroll
    for (int f = 0; f < 4; ++f)
      #pragma unroll
      for (int r = 0; r < 4; ++r) {
        float e = __expf(p[f][r] - m_new);
        p[f][r] = e;
        tsum += e;
      }
    tsum += __shfl_xor(tsum, 16);
    tsum += __shfl_xor(tsum, 32);
    l_run = l_run * fac + tsum;
    m_run = m_new;
    bfx8 pa0, pa1;
    #pragma unroll
    for (int r = 0; r < 4; ++r) {
      pa0[r] = (__bf16)p[0][r];  pa0[r + 4] = (__bf16)p[1][r];
      pa1[r] = (__bf16)p[2][r];  pa1[r + 4] = (__bf16)p[3][r];
    }
    float f0 = __shfl(fac, kb + 0), f1 = __shfl(fac, kb + 1);
    float f2 = __shfl(fac, kb + 2), f3 = __shfl(fac, kb + 3);
    o0[0] *= f0; o0[1] *= f1; o0[2] *= f2; o0[3] *= f3;
    o1[0] *= f0; o1[1] *= f1; o1[2] *= f2; o1[3] *= f3;
    #pragma unroll
    for (int s = 0; s < 2; ++s) {
      bfx8 pa = s ? pa1 : pa0;
      #pragma unroll
      for (int df = 0; df < 2; ++df) {
        bfx4 vlo = *(const bfx4*)&Vt[16 * df + lr][s * 32 + kb];
        bfx4 vhi = *(const bfx4*)&Vt[16 * df + lr][s * 32 + kb + 16];
        bfx8 vf = __builtin_shufflevector(vlo, vhi, 0, 1, 2, 3, 4, 5, 6, 7);
        if (df == 0) o0 = __builtin_amdgcn_mfma_f32_16x16x32_bf16(pa, vf, o0, 0, 0, 0);
        else         o1 = __builtin_amdgcn_mfma_f32_16x16x32_bf16(pa, vf, o1, 0, 0, 0);
      }
    }
  }
  float il[4];
  #pragma unroll
  for (int r = 0; r < 4; ++r) il[r] = 1.f / __shfl(l_run, kb + r);
  const size_t obase = (size_t)b * NTOK * CDIM + (size_t)h * DHEAD;
  #pragma unroll
  for (int r = 0; r < 4; ++r) {
    size_t rowoff = obase + (size_t)(q0 + 16 * w + kb + r) * CDIM;
    outb[rowoff + lr]      = (__bf16)(o0[r] * il[r]);
    outb[rowoff + 16 + lr] = (__bf16)(o1[r] * il[r]);
  }
}

// ---------------------------------------------------------------------------
extern "C" void kernel_launch(void* const* d_in, const int* in_sizes, int n_in,
                              void* d_out, int out_size, void* d_ws, size_t ws_size,
                              hipStream_t stream) {
  const float* x     = (const float*)d_in[0];
  const float* ln1_g = (const float*)d_in[2];
  const float* ln1_b = (const float*)d_in[3];
  const float* Wqkv  = (const float*)d_in[4];
  const float* table = (const float*)d_in[5];
  const float* Wo    = (const float*)d_in[6];
  const float* bo    = (const float*)d_in[7];
  const float* ln2_g = (const float*)d_in[8];
  const float* ln2_b = (const float*)d_in[9];
  const float* W1    = (const float*)d_in[10];
  const float* b1    = (const float*)d_in[11];
  const float* W2    = (const float*)d_in[12];
  const float* b2    = (const float*)d_in[13];

  char* ws = (char*)d_ws;
  float*  t     = (float*)(ws + 0);           // 16 MB (reused as y)
  float*  t2    = (float*)(ws + 16777216);    // 16 MB
  __bf16* qkv   = (__bf16*)(ws + 33554432);   // 24 MB
  __bf16* hln   = (__bf16*)(ws + 58720256);   // 8 MB (reused for ln2)
  __bf16* aout  = (__bf16*)(ws + 67108864);   // 8 MB
  __bf16* hid   = (__bf16*)(ws + 75497472);   // 16 MB
  __bf16* biasT = (__bf16*)(ws + 92274688);   // 16 MB
  __bf16* Wqkvt = (__bf16*)(ws + 109051904);
  __bf16* Wot   = (__bf16*)(ws + 109445120);
  __bf16* W1t   = (__bf16*)(ws + 109576192);
  __bf16* W2t   = (__bf16*)(ws + 109838336);  // ends 110100480
  if (ws_size < 110100480) return;            // visible failure instead of OOB
  float* y = t;

  wprep_kernel<<<768, 256, 0, stream>>>(Wqkv, Wqkvt, 256, 768);
  wprep_kernel<<<256, 256, 0, stream>>>(Wo, Wot, 256, 256);
  wprep_kernel<<<512, 256, 0, stream>>>(W1, W1t, 256, 512);
  wprep_kernel<<<512, 256, 0, stream>>>(W2, W2t, 512, 256);
  bias_kernel<<<32768, 256, 0, stream>>>(table, biasT);
  transpose_kernel<<<dim3(32, 8, 16), 256, 0, stream>>>(x, t, 256, 1024);
  ln_kernel<<<4096, 256, 0, stream>>>(t, ln1_g, ln1_b, hln);
  gemm_kernel<0><<<dim3(256, 12), 256, 0, stream>>>(hln, Wqkvt, nullptr, nullptr, qkv, 16384, 768, 256);
  attn_kernel<<<dim3(16, 8, 16), 256, 0, stream>>>(qkv, biasT, aout);
  gemm_kernel<1><<<dim3(256, 4), 256, 0, stream>>>(aout, Wot, bo, t, t2, 16384, 256, 256);
  ln_kernel<<<4096, 256, 0, stream>>>(t2, ln2_g, ln2_b, hln);
  gemm_kernel<2><<<dim3(256, 8), 256, 0, stream>>>(hln, W1t, b1, nullptr, hid, 16384, 512, 256);
  gemm_kernel<1><<<dim3(256, 4), 256, 0, stream>>>(hid, W2t, b2, t2, y, 16384, 256, 512);
  transpose_kernel<<<dim3(8, 32, 16), 256, 0, stream>>>(y, (float*)d_out, 1024, 256);
}